// Round 10
// baseline (3144.852 us; speedup 1.0000x reference)
//
#include <hip/hip_runtime.h>
#include <hip/hip_bf16.h>
#include <cmath>

#define HID 512
#define TSTEPS 784
#define BATCH 256
#define NCLS 10
#define NBLK 256
#define NGRP 16     // groups (16 batch rows each), 16 blocks x 32 cols

typedef __bf16 bf16x8 __attribute__((ext_vector_type(8)));
typedef float f32x4 __attribute__((ext_vector_type(4)));
typedef float f32x2 __attribute__((ext_vector_type(2)));
typedef int   i32x4 __attribute__((ext_vector_type(4)));
typedef int   i32x2 __attribute__((ext_vector_type(2)));

#define SWS(r) (((unsigned)(r) & 7u) << 4)

// LLC-coherent ops (bypass L1+L2; proven cross-XCD-visible rounds 4/5/9)
#define LDX4_CC(dst, addr) \
    asm volatile("global_load_dwordx4 %0, %1, off sc0 sc1" : "=v"(dst) : "v"(addr) : "memory")
#define STX2_CC(addr, val) \
    asm volatile("global_store_dwordx2 %0, %1, off sc0 sc1" :: "v"(addr), "v"(val) : "memory")

// zero h0+h1 (fp32 tagged, 1MB total); transpose x -> xT[784][256]
__global__ void init_all(const float* __restrict__ x, float* __restrict__ xT,
                         uint4* __restrict__ hz) {
    int t = blockIdx.x, tid = threadIdx.x;
    xT[t * BATCH + tid] = x[tid * TSTEPS + t];
    int i = t * 256 + tid;
    if (i < (1 << 20) / 16) hz[i] = make_uint4(0u, 0u, 0u, 0u);
}

__device__ __forceinline__ float sigmoid_f(float v) {
    return __fdividef(1.f, 1.f + __expf(-v));
}
__device__ __forceinline__ float tanh_f(float v) {
    float e = __expf(fminf(fmaxf(2.f * v, -30.f), 30.f));
    return __fdividef(e - 1.f, e + 1.f);
}

// Persistent LSTM, self-validating tagged-h exchange.
// 256 blocks = 16 groups(16 batch rows) x 16 col-slices(32 cols).
// h buffers fp32: top16 = RTN bf16 value, low8 = step tag. One dword is
// atomically {value,tag} -> producer stores are fire-and-forget (no flush,
// no flags); consumer poll IS the data load. 3 barriers/step, 1 coherent RT.
__global__ __launch_bounds__(512)
void lstm_persist(const float* __restrict__ xT,     // [784][256]
                  const float* __restrict__ W_hh,   // [2048][512] fp32
                  const float* __restrict__ w_in,   // [2048]
                  const float* __restrict__ b_ih,
                  const float* __restrict__ b_hh,
                  float* __restrict__ h0,           // [256][512] tagged fp32
                  float* __restrict__ h1,
                  float* __restrict__ hf)           // [256][512] fp32 (final h)
{
    __shared__ __align__(16) __bf16 wlds[128 * HID];  // 128 KB, XOR-swizzled
    __shared__ __align__(16) __bf16 hlds[16 * HID];   // 16 KB, XOR-swizzled
    __shared__ float gl[4][16][33];                   // gate exchange
    __shared__ float xl[16];

    const int tid  = threadIdx.x;
    const int lane = tid & 63;
    const int w    = tid >> 6;           // wave 0..7
    const int s    = w & 3;              // gate (i,f,g,o)
    const int ch   = w >> 2;             // col half (16 cols each)
    const int bg   = blockIdx.x >> 4;    // group (16)
    const int cs   = blockIdx.x & 15;    // col slice (16)
    const int b0   = bg * 16;
    const int j0   = cs * 32;
    const int rlo  = lane & 15;
    const int khi  = (lane >> 4) * 8;    // elements

    // ---- stage W slice (128 rows x 512) into LDS once (fp32->bf16, swizzled) ----
    {
        int r = tid >> 2;                // local row 0..127
        int q = tid & 3;
        int gs = r >> 5, jj = r & 31;
        const float* src = W_hh + (size_t)(gs * HID + j0 + jj) * HID + q * 128;
        char* wp = (char*)wlds;
        unsigned rowb = (unsigned)r * (HID * 2);
        unsigned sw   = SWS(r);
        #pragma unroll
        for (int cc = 0; cc < 128; cc += 8) {
            float4 va = *(const float4*)(src + cc);
            float4 vb = *(const float4*)(src + cc + 4);
            bf16x8 pk;
            pk[0]=(__bf16)va.x; pk[1]=(__bf16)va.y; pk[2]=(__bf16)va.z; pk[3]=(__bf16)va.w;
            pk[4]=(__bf16)vb.x; pk[5]=(__bf16)vb.y; pk[6]=(__bf16)vb.z; pk[7]=(__bf16)vb.w;
            *(bf16x8*)(wp + ((rowb + (unsigned)(q * 128 + cc) * 2) ^ sw)) = pk;
        }
    }

    // cell mapping (tid<256): row Rc=tid>>4 (0..15), cols c2,c2+1 (of 32)
    const int Rc = tid >> 4;
    const int c2 = (tid & 15) * 2;
    float win_r[4][2], bias_r[4][2];
    #pragma unroll
    for (int g = 0; g < 4; ++g)
        #pragma unroll
        for (int ii = 0; ii < 2; ++ii) {
            int idx = g * HID + j0 + c2 + ii;
            win_r[g][ii]  = w_in[idx];
            bias_r[g][ii] = b_ih[idx] + b_hh[idx];
        }
    float creg[2] = {0.f, 0.f};

    // staging mapping: row rS (0..15), segment seg (0..31) of 16 fp32 cols (64B)
    const int rS  = tid & 15;
    const int seg = tid >> 4;
    const unsigned rowbS = (unsigned)rS * (HID * 2);
    const unsigned swS   = SWS(rS);

    // B-fragment base: local W row rB = s*32 + ch*16 + rlo
    const unsigned rBb = (unsigned)(s * 32 + ch * 16 + rlo) * (HID * 2);
    const unsigned swB = SWS(rlo);
    const char* wbp = (const char*)wlds;
    const char* hbp = (const char*)hlds;
    char* hwp = (char*)hlds;

    __syncthreads();

    for (int t = 0; t < TSTEPS; ++t) {
        const float* hprev = (t & 1) ? h1 : h0;
        float* hnext       = (t & 1) ? h0 : h1;

        // ---- stage: poll-load own 64B fragment until all 16 tags == t ----
        {
            const float* gsrc = hprev + (size_t)(b0 + rS) * HID + seg * 16;
            const unsigned tag = (unsigned)(t & 0xFF);
            i32x4 v0, v1, v2, v3;
            for (;;) {
                LDX4_CC(v0, gsrc);     LDX4_CC(v1, gsrc + 4);
                LDX4_CC(v2, gsrc + 8); LDX4_CC(v3, gsrc + 12);
                asm volatile("s_waitcnt vmcnt(0)" ::: "memory");
                unsigned bad = 0;
                #pragma unroll
                for (int k = 0; k < 4; ++k) {
                    bad |= ((unsigned)v0[k] ^ tag) & 0xFFu;
                    bad |= ((unsigned)v1[k] ^ tag) & 0xFFu;
                    bad |= ((unsigned)v2[k] ^ tag) & 0xFFu;
                    bad |= ((unsigned)v3[k] ^ tag) & 0xFFu;
                }
                if (!bad) break;
                __builtin_amdgcn_s_sleep(1);
            }
            __builtin_amdgcn_sched_barrier(0);
            // pack high-16s (exact bf16, producer pre-rounded) into LDS
            i32x4 o0, o1;
            o0[0] = (int)(((unsigned)v0[0] >> 16) | ((unsigned)v0[1] & 0xFFFF0000u));
            o0[1] = (int)(((unsigned)v0[2] >> 16) | ((unsigned)v0[3] & 0xFFFF0000u));
            o0[2] = (int)(((unsigned)v1[0] >> 16) | ((unsigned)v1[1] & 0xFFFF0000u));
            o0[3] = (int)(((unsigned)v1[2] >> 16) | ((unsigned)v1[3] & 0xFFFF0000u));
            o1[0] = (int)(((unsigned)v2[0] >> 16) | ((unsigned)v2[1] & 0xFFFF0000u));
            o1[1] = (int)(((unsigned)v2[2] >> 16) | ((unsigned)v2[3] & 0xFFFF0000u));
            o1[2] = (int)(((unsigned)v3[0] >> 16) | ((unsigned)v3[1] & 0xFFFF0000u));
            o1[3] = (int)(((unsigned)v3[2] >> 16) | ((unsigned)v3[3] & 0xFFFF0000u));
            unsigned base = rowbS + (unsigned)seg * 32u;
            *(i32x4*)(hwp + ((base +  0u) ^ swS)) = o0;
            *(i32x4*)(hwp + ((base + 16u) ^ swS)) = o1;
        }
        if (tid < 16) xl[tid] = xT[t * BATCH + b0 + tid];
        __syncthreads();   // A: hlds + xl ready

        // ---- gates tile: 16 rows x 16 cols for gate s, col-half ch ----
        f32x4 acc0 = {0.f,0.f,0.f,0.f};
        #pragma unroll
        for (int ks = 0; ks < 16; ++ks) {
            unsigned colb = (unsigned)(khi * 2 + ks * 64);
            bf16x8 a0 = *(const bf16x8*)(hbp + (((unsigned)rlo * 1024u + colb) ^ SWS(rlo)));
            bf16x8 b  = *(const bf16x8*)(wbp + ((rBb + colb) ^ swB));
            acc0 = __builtin_amdgcn_mfma_f32_16x16x32_bf16(a0, b, acc0, 0, 0, 0);
        }
        #pragma unroll
        for (int rr = 0; rr < 4; ++rr) {
            int rowl = (lane >> 4) * 4 + rr;   // D: col=lane&15, row=(lane>>4)*4+reg
            gl[s][rowl][ch * 16 + rlo] = acc0[rr];
        }
        __syncthreads();   // A2: gl ready

        // ---- cell update (tid<256: 2 cols), tagged fire-and-forget h store ----
        if (tid < 256) {
            float xv = xl[Rc];
            float hn2[2];
            #pragma unroll
            for (int ii = 0; ii < 2; ++ii) {
                int ccx = c2 + ii;
                float gi = gl[0][Rc][ccx] + xv * win_r[0][ii] + bias_r[0][ii];
                float gf = gl[1][Rc][ccx] + xv * win_r[1][ii] + bias_r[1][ii];
                float gg = gl[2][Rc][ccx] + xv * win_r[2][ii] + bias_r[2][ii];
                float go = gl[3][Rc][ccx] + xv * win_r[3][ii] + bias_r[3][ii];
                float cn = sigmoid_f(gf) * creg[ii] + sigmoid_f(gi) * tanh_f(gg);
                creg[ii] = cn;
                hn2[ii]  = sigmoid_f(go) * tanh_f(cn);
            }
            if (t == TSTEPS - 1) {
                *(f32x2*)(hf + (size_t)(b0 + Rc) * HID + j0 + c2) = (f32x2){hn2[0], hn2[1]};
            } else {
                const unsigned tagn = (unsigned)((t + 1) & 0xFF);
                union { float f; unsigned u; } a0u, a1u;
                a0u.f = (float)(__bf16)hn2[0];   // RTN to bf16, low 16 bits zero
                a1u.f = (float)(__bf16)hn2[1];
                i32x2 st;
                st[0] = (int)(a0u.u | tagn);
                st[1] = (int)(a1u.u | tagn);
                float* dst = hnext + (size_t)(b0 + Rc) * HID + j0 + c2;
                STX2_CC(dst, st);
            }
        }
        __syncthreads();   // B: gl/xl consumed; safe to restage next step
    }
}

// out[b][j] = h_T[b] . W_lin[j] + b_lin[j]
__global__ void head(const float* __restrict__ hfp, const float* __restrict__ Wl,
                     const float* __restrict__ bl_, float* __restrict__ out)
{
    __shared__ float hr[HID];
    int b = blockIdx.x;
    for (int k = threadIdx.x; k < HID; k += blockDim.x) hr[k] = hfp[b * HID + k];
    __syncthreads();
    int j = threadIdx.x;
    if (j < NCLS) {
        float acc = bl_[j];
        for (int k = 0; k < HID; ++k) acc += hr[k] * Wl[j * HID + k];
        out[b * NCLS + j] = acc;
    }
}

extern "C" void kernel_launch(void* const* d_in, const int* in_sizes, int n_in,
                              void* d_out, int out_size, void* d_ws, size_t ws_size,
                              hipStream_t stream) {
    const float* inputs = (const float*)d_in[0];
    const float* W_ih   = (const float*)d_in[1];
    const float* W_hh   = (const float*)d_in[2];
    const float* b_ih   = (const float*)d_in[3];
    const float* b_hh   = (const float*)d_in[4];
    const float* W_lin  = (const float*)d_in[5];
    const float* b_lin  = (const float*)d_in[6];

    // ws: h0 512K | h1 512K | hf 512K | xT 784K
    const size_t OFS_H1 = 512u << 10;
    const size_t OFS_HF = 1024u << 10;
    const size_t OFS_XT = 1536u << 10;
    const size_t NEEDED = OFS_XT + (size_t)TSTEPS * BATCH * 4;
    if (ws_size < NEEDED) return;

    char* ws = (char*)d_ws;
    float* h0 = (float*)ws;
    float* h1 = (float*)(ws + OFS_H1);
    float* hf = (float*)(ws + OFS_HF);
    float* xT = (float*)(ws + OFS_XT);

    init_all<<<TSTEPS, BATCH, 0, stream>>>(inputs, xT, (uint4*)ws);

    lstm_persist<<<NBLK, 512, 0, stream>>>(xT, W_hh, W_ih, b_ih, b_hh,
                                           h0, h1, hf);

    head<<<BATCH, 64, 0, stream>>>(hf, W_lin, b_lin, (float*)d_out);
}